// Round 6
// baseline (215.106 us; speedup 1.0000x reference)
//
#include <hip/hip_runtime.h>
#include <math.h>

#define NB 32
#define NN 262144
#define NG 256
#define NC 64             // chunks per batch (sort passes)
#define CH (NN/NC)        // 4096 elements per chunk
#define SC (CH/4)         // 1024 elements per wave (4 waves/block)
#define CD 64             // chunks per batch, apply pass
#define ELD (NN/CD)       // 4096 elements per apply block

// ---------------- Pass 1: per-(batch,chunk,group) counts ----------------
__global__ __launch_bounds__(256) void k_count(const int* __restrict__ vr,
                                               unsigned* __restrict__ cnt){
  __shared__ unsigned scnt[NG];
  const int t = threadIdx.x;
  scnt[t] = 0u;
  __syncthreads();

  const int b = blockIdx.x / NC;
  const int c = blockIdx.x % NC;
  const size_t base = (size_t)b*NN + (size_t)c*CH;
  const int4* v4 = (const int4*)(vr + base);

#pragma unroll
  for (int i = 0; i < CH/1024; i++){
    int4 v = v4[i*256 + t];
    atomicAdd(&scnt[v.x], 1u);
    atomicAdd(&scnt[v.y], 1u);
    atomicAdd(&scnt[v.z], 1u);
    atomicAdd(&scnt[v.w], 1u);
  }
  __syncthreads();
  cnt[(size_t)(b*NC + c)*NG + t] = scnt[t];
}

// ---- Pass 2: rewrite cnt into absolute scatter offsets; emit group base/len ----
__global__ __launch_bounds__(256) void k_offsets(unsigned* __restrict__ cnt,
                                                 unsigned* __restrict__ grpbase,
                                                 unsigned* __restrict__ grplen){
  const int b = blockIdx.x;
  const int g = threadIdx.x;
  unsigned tot = 0;
#pragma unroll 8
  for (int c = 0; c < NC; c++) tot += cnt[(size_t)(b*NC + c)*NG + g];

  __shared__ unsigned ss[NG];
  ss[g] = tot; __syncthreads();
  for (int d = 1; d < NG; d <<= 1){
    unsigned v = (g >= d) ? ss[g - d] : 0u;
    __syncthreads();
    ss[g] += v;
    __syncthreads();
  }
  unsigned base = ss[g] - tot;   // exclusive prefix over groups

  unsigned run = base;
  for (int c = 0; c < NC; c++){
    size_t idx = (size_t)(b*NC + c)*NG + g;
    unsigned x = cnt[idx];
    cnt[idx] = run;
    run += x;
  }
  grpbase[b*NG + g] = base;
  grplen [b*NG + g] = tot;
}

// ---- Pass 3: LDS-staged stable sort of each chunk + coalesced flush ----
// Stability: waves own contiguous sub-chunks in wave-index order; per-wave
// running counters seeded with cross-wave prefix -> global element order kept
// bit-exactly (the fp32 sum chain downstream depends on it).
__global__ __launch_bounds__(256) void k_scatter(const float* __restrict__ pr,
                                                 const int* __restrict__ vr,
                                                 const unsigned* __restrict__ off,
                                                 float* __restrict__ sorted){
  __shared__ float vbuf[CH];            // 16 KB sorted values
  __shared__ unsigned graw32[CH/4];     // 4 KB raw group ids (packed u8x4, elem order)
  __shared__ unsigned char gbuf[CH];    // 4 KB group id per sorted slot
  __shared__ unsigned wcnt[4][NG];      // per-wave histogram -> running counters
  __shared__ unsigned bias[NG];         // global_dest - local_base per group
  __shared__ unsigned ss[NG];           // scan scratch
  const int t    = threadIdx.x;
  const int lane = t & 63;
  const int w    = t >> 6;
  const int b = blockIdx.x / NC;
  const int c = blockIdx.x % NC;
  const size_t base = (size_t)b*NN + (size_t)c*CH;

#pragma unroll
  for (int k = 0; k < 4; k++) wcnt[k][t] = 0u;
  __syncthreads();

  // phase 1: per-wave histogram over its sub-chunk + stage packed group ids
  {
    const int4* v4 = (const int4*)(vr + base + (size_t)w*SC);
#pragma unroll
    for (int i = 0; i < SC/256; i++){      // 4 iters
      int4 v = v4[i*64 + lane];
      atomicAdd(&wcnt[w][v.x], 1u);
      atomicAdd(&wcnt[w][v.y], 1u);
      atomicAdd(&wcnt[w][v.z], 1u);
      atomicAdd(&wcnt[w][v.w], 1u);
      graw32[w*(SC/4) + i*64 + lane] =
        (unsigned)v.x | ((unsigned)v.y << 8) | ((unsigned)v.z << 16) | ((unsigned)v.w << 24);
    }
  }
  __syncthreads();

  // phase 2: local offsets (thread t == group id)
  {
    unsigned c0 = wcnt[0][t], c1 = wcnt[1][t], c2 = wcnt[2][t], c3 = wcnt[3][t];
    unsigned tot = c0 + c1 + c2 + c3;
    ss[t] = tot; __syncthreads();
    for (int d = 1; d < NG; d <<= 1){
      unsigned v = (t >= d) ? ss[t - d] : 0u;
      __syncthreads();
      ss[t] += v;
      __syncthreads();
    }
    unsigned lb = ss[t] - tot;              // local exclusive prefix over groups
    wcnt[0][t] = lb;
    wcnt[1][t] = lb + c0;
    wcnt[2][t] = lb + c0 + c1;
    wcnt[3][t] = lb + c0 + c1 + c2;
    bias[t] = off[(size_t)(b*NC + c)*NG + t] - lb;
  }
  __syncthreads();

  // phase 3: stable scatter into LDS (per wave, element order; g fed from LDS)
  {
    const unsigned long long below = (lane == 0) ? 0ull : ((1ull << lane) - 1ull);
    const float* psrc = pr + base + (size_t)w*SC;
    const int shft = (lane & 3) * 8;
    for (int s = 0; s < SC/64; s++){       // 16 stripes
      float p = psrc[s*64 + lane];
      // same-word broadcast read: 4 lanes share one dword, free on LDS
      unsigned packed = graw32[w*(SC/4) + s*16 + (lane >> 2)];
      int g = (int)((packed >> shft) & 255u);
      unsigned long long mask = ~0ull;
#pragma unroll
      for (int bit = 0; bit < 8; bit++){
        int bv = (g >> bit) & 1;
        unsigned long long bal = __ballot(bv);
        mask &= bv ? bal : ~bal;
      }
      int rank = __popcll(mask & below);
      unsigned old = wcnt[w][g];                 // all lanes read pre-update value
      if (rank == 0) wcnt[w][g] = old + (unsigned)__popcll(mask);
      vbuf[old + (unsigned)rank] = p;
      gbuf[old + (unsigned)rank] = (unsigned char)g;
    }
  }
  __syncthreads();

  // phase 4: coalesced flush (consecutive p -> consecutive dest within group runs)
  {
    float* dst = sorted + (size_t)b*NN;
    const unsigned* gbuf32 = (const unsigned*)gbuf;
#pragma unroll
    for (int k = 0; k < CH/256; k++){
      int p = k*256 + t;
      unsigned packed = gbuf32[p >> 2];    // broadcast within 4 threads
      unsigned g = (packed >> ((p & 3) * 8)) & 255u;
      dst[bias[g] + (unsigned)p] = vbuf[p];
    }
  }
}

// ---- Pass 4: one LANE per (batch,group): each lane walks its group's
//      contiguous sorted slice running the bit-exact element-order fp32 chain;
//      min/max (order-independent) fused into the same loop. No LDS. ----
__global__ __launch_bounds__(64) void k_sum(const float* __restrict__ sorted,
                                            const unsigned* __restrict__ grpbase,
                                            const unsigned* __restrict__ grplen,
                                            float* __restrict__ gsum,
                                            float* __restrict__ gmn,
                                            float* __restrict__ gmx){
  const int lane = threadIdx.x;
  const int b = blockIdx.x >> 2;                  // 4 waves per batch
  const int g = ((blockIdx.x & 3) << 6) + lane;   // one group per lane

  const unsigned base = grpbase[b*NG + g];
  const unsigned len  = grplen [b*NG + g];
  const float* src = sorted + (size_t)b*NN + base;

  float s = 0.0f, mn = INFINITY, mx = -INFINITY;
  unsigned i = 0;
  const unsigned n8 = len & ~7u;
  for (; i < n8; i += 8){
    // 8 independent loads issue ahead of the dependent add chain
    float v0 = src[i+0], v1 = src[i+1], v2 = src[i+2], v3 = src[i+3];
    float v4 = src[i+4], v5 = src[i+5], v6 = src[i+6], v7 = src[i+7];
    s = __fadd_rn(s, v0); s = __fadd_rn(s, v1);
    s = __fadd_rn(s, v2); s = __fadd_rn(s, v3);
    s = __fadd_rn(s, v4); s = __fadd_rn(s, v5);
    s = __fadd_rn(s, v6); s = __fadd_rn(s, v7);
    mn = fminf(mn, fminf(fminf(v0, v1), fminf(v2, v3)));
    mn = fminf(mn, fminf(fminf(v4, v5), fminf(v6, v7)));
    mx = fmaxf(mx, fmaxf(fmaxf(v0, v1), fmaxf(v2, v3)));
    mx = fmaxf(mx, fmaxf(fmaxf(v4, v5), fmaxf(v6, v7)));
  }
  for (; i < len; i++){
    float v = src[i];
    s = __fadd_rn(s, v);
    mn = fminf(mn, v);
    mx = fmaxf(mx, v);
  }
  gsum[b*NG + g] = s;
  gmn [b*NG + g] = mn;
  gmx [b*NG + g] = mx;
}

// ---- Pass 5: per-batch group pipeline (blend, stable rank, f0/f1, no_scale) ----
__global__ __launch_bounds__(256) void k_pipeline(const float* __restrict__ gsum,
                                                  const float* __restrict__ gmn,
                                                  const float* __restrict__ gmx,
                                                  const float* __restrict__ inp_means,
                                                  const float* __restrict__ Wv,
                                                  float4* __restrict__ params){
  const int b = blockIdx.x;
  const int g = threadIdx.x;
  __shared__ float vm[NG];
  __shared__ float vs[NG];

  const float s   = gsum[b*NG + g];   // empty group: len==0 -> s==0 (matches where(vany,...))
  const float mnf = gmn [b*NG + g];
  const float mxf = gmx [b*NG + g];
  const float W0 = Wv[0], W1 = Wv[1];
  float mean = __fdiv_rn(__fadd_rn(__fmul_rn(inp_means[b*NG + g], W0),
                                   __fmul_rn(s, W1)),
                         __fadd_rn(W0, W1));
  vm[g] = mean;
  __syncthreads();

  // stable rank == position after stable argsort
  int r = 0;
  for (int j = 0; j < NG; j++){
    float x = vm[j];
    r += (x < mean) || (x == mean && j < g);
  }
  vs[r] = mean;
  __syncthreads();

  float c0 = (r == 0)    ? vs[0]                     : vs[r-1];
  float c1 = vs[r];
  float c2 = (r == NG-1) ? __fmul_rn(vs[NG-1], 2.0f) : vs[r+1];
  float f0 = __fdiv_rn(__fadd_rn(c0, c1), 1.999f);
  float f1 = __fdiv_rn(__fadd_rn(c1, c2), 2.001f);

  bool ns = (mnf == mxf);
  float4 q;
  q.x = ns ? 0.0f : mnf;                       // vmin_use
  q.y = ns ? 1.0f : __fsub_rn(mxf, mnf);       // range_use
  q.z = ns ? 1.0f : __fsub_rn(f1, f0);         // (f1-f0)_use
  q.w = ns ? 0.0f : f0;                        // f0_use
  params[b*NG + g] = q;
}

// ---- Pass 6: per-element apply, fp32 replicating reference op order ----
static __device__ __forceinline__ float apply_one(float p, int g, const float4* __restrict__ sp){
  float4 q = sp[g];
  float t1  = __fsub_rn(p, q.x);
  float t3  = __fdiv_rn(t1, q.y);
  float t5  = __fmul_rn(t3, q.z);
  float tmp = __fadd_rn(t5, q.w);
  bool bad = __builtin_isnan(tmp) || (tmp == 0.0f);
  float s = __fdiv_rn(p, bad ? 1.0f : tmp);
  bool bad2 = bad || __builtin_isnan(s) || __builtin_isinf(s);
  float sc = bad2 ? 0.0f : s;
  return __fmul_rn(p, sc);
}

__global__ __launch_bounds__(256) void k_apply(const float* __restrict__ pr,
                                               const int* __restrict__ vr,
                                               const float4* __restrict__ params,
                                               float* __restrict__ out){
  __shared__ float4 sp[NG];
  const int t = threadIdx.x;
  const int b = blockIdx.x / CD;
  const int c = blockIdx.x % CD;

  sp[t] = params[b*NG + t];
  __syncthreads();

  const size_t base = (size_t)b*NN + (size_t)c*ELD;
  const float4* p4 = (const float4*)(pr + base);
  const int4*  v4 = (const int4*)(vr + base);
  float4* o4 = (float4*)(out + base);

#pragma unroll
  for (int i = 0; i < ELD/1024; i++){
    float4 p = p4[i*256 + t];
    int4   v = v4[i*256 + t];
    float4 r;
    r.x = apply_one(p.x, v.x, sp);
    r.y = apply_one(p.y, v.y, sp);
    r.z = apply_one(p.z, v.z, sp);
    r.w = apply_one(p.w, v.w, sp);
    o4[i*256 + t] = r;
  }
}

extern "C" void kernel_launch(void* const* d_in, const int* in_sizes, int n_in,
                              void* d_out, int out_size, void* d_ws, size_t ws_size,
                              hipStream_t stream){
  const float* pr        = (const float*)d_in[0];
  const float* inp_means = (const float*)d_in[1];
  const int*   vr        = (const int*)d_in[2];
  const float* W         = (const float*)d_in[3];
  float* out = (float*)d_out;

  char* ws = (char*)d_ws;
  size_t o = 0;
  unsigned* cnt     = (unsigned*)(ws + o); o += (size_t)NB*NC*NG*4;  // 2 MB
  unsigned* grpbase = (unsigned*)(ws + o); o += (size_t)NB*NG*4;     // 32 KB
  unsigned* grplen  = (unsigned*)(ws + o); o += (size_t)NB*NG*4;
  float*    gsum    = (float*)   (ws + o); o += (size_t)NB*NG*4;
  float*    gmn     = (float*)   (ws + o); o += (size_t)NB*NG*4;
  float*    gmx     = (float*)   (ws + o); o += (size_t)NB*NG*4;
  float4*   params  = (float4*)  (ws + o); o += (size_t)NB*NG*16;    // 128 KB
  // sorted values live in d_out (fully overwritten by k_apply afterwards)
  float* sorted = out;

  k_count   <<<NB*NC, 256, 0, stream>>>(vr, cnt);
  k_offsets <<<NB,     NG, 0, stream>>>(cnt, grpbase, grplen);
  k_scatter <<<NB*NC, 256, 0, stream>>>(pr, vr, cnt, sorted);
  k_sum     <<<NB*4,   64, 0, stream>>>(sorted, grpbase, grplen, gsum, gmn, gmx);
  k_pipeline<<<NB,     NG, 0, stream>>>(gsum, gmn, gmx, inp_means, W, params);
  k_apply   <<<NB*CD, 256, 0, stream>>>(pr, vr, params, out);
}

// Round 7
// 182.671 us; speedup vs baseline: 1.1776x; 1.1776x over previous
//
#include <hip/hip_runtime.h>
#include <math.h>

#define NB 32
#define NN 262144
#define NG 256
#define NC 64             // chunks per batch (sort passes)
#define CH (NN/NC)        // 4096 elements per chunk
#define SC (CH/4)         // 1024 elements per wave (4 waves/block)
#define CD 64             // chunks per batch, apply pass
#define ELD (NN/CD)       // 4096 elements per apply block

// ---------------- Pass 1: per-(batch,chunk,group) counts ----------------
__global__ __launch_bounds__(256) void k_count(const int* __restrict__ vr,
                                               unsigned* __restrict__ cnt){
  __shared__ unsigned scnt[NG];
  const int t = threadIdx.x;
  scnt[t] = 0u;
  __syncthreads();

  const int b = blockIdx.x / NC;
  const int c = blockIdx.x % NC;
  const size_t base = (size_t)b*NN + (size_t)c*CH;
  const int4* v4 = (const int4*)(vr + base);

#pragma unroll
  for (int i = 0; i < CH/1024; i++){
    int4 v = v4[i*256 + t];
    atomicAdd(&scnt[v.x], 1u);
    atomicAdd(&scnt[v.y], 1u);
    atomicAdd(&scnt[v.z], 1u);
    atomicAdd(&scnt[v.w], 1u);
  }
  __syncthreads();
  cnt[(size_t)(b*NC + c)*NG + t] = scnt[t];
}

// ---- Pass 2: rewrite cnt into absolute scatter offsets; emit group base/len ----
__global__ __launch_bounds__(256) void k_offsets(unsigned* __restrict__ cnt,
                                                 unsigned* __restrict__ grpbase,
                                                 unsigned* __restrict__ grplen){
  const int b = blockIdx.x;
  const int g = threadIdx.x;

  unsigned v[NC];                         // all chunk counts in regs (loads pipeline)
#pragma unroll
  for (int c = 0; c < NC; c++) v[c] = cnt[(size_t)(b*NC + c)*NG + g];
  unsigned tot = 0;
#pragma unroll
  for (int c = 0; c < NC; c++) tot += v[c];

  __shared__ unsigned ss[NG];
  ss[g] = tot; __syncthreads();
  for (int d = 1; d < NG; d <<= 1){
    unsigned x = (g >= d) ? ss[g - d] : 0u;
    __syncthreads();
    ss[g] += x;
    __syncthreads();
  }
  unsigned base = ss[g] - tot;   // exclusive prefix over groups

  unsigned run = base;
#pragma unroll
  for (int c = 0; c < NC; c++){
    cnt[(size_t)(b*NC + c)*NG + g] = run;
    run += v[c];
  }
  grpbase[b*NG + g] = base;
  grplen [b*NG + g] = tot;
}

// ---- Pass 3: LDS-staged stable sort of each chunk + coalesced flush ----
// Stability: waves own contiguous sub-chunks in wave-index order; per-wave
// running counters seeded with cross-wave prefix -> global element order kept
// bit-exactly (the fp32 sum chain downstream depends on it).
__global__ __launch_bounds__(256) void k_scatter(const float* __restrict__ pr,
                                                 const int* __restrict__ vr,
                                                 const unsigned* __restrict__ off,
                                                 float* __restrict__ sorted){
  __shared__ float vbuf[CH];            // 16 KB sorted values
  __shared__ unsigned graw32[CH/4];     // 4 KB raw group ids (packed u8x4, elem order)
  __shared__ unsigned char gbuf[CH];    // 4 KB group id per sorted slot
  __shared__ unsigned wcnt[4][NG];      // per-wave histogram -> running counters
  __shared__ unsigned bias[NG];         // global_dest - local_base per group
  __shared__ unsigned ss[NG];           // scan scratch
  const int t    = threadIdx.x;
  const int lane = t & 63;
  const int w    = t >> 6;
  const int b = blockIdx.x / NC;
  const int c = blockIdx.x % NC;
  const size_t base = (size_t)b*NN + (size_t)c*CH;

#pragma unroll
  for (int k = 0; k < 4; k++) wcnt[k][t] = 0u;
  __syncthreads();

  // phase 1: per-wave histogram over its sub-chunk + stage packed group ids
  {
    const int4* v4 = (const int4*)(vr + base + (size_t)w*SC);
#pragma unroll
    for (int i = 0; i < SC/256; i++){      // 4 iters
      int4 v = v4[i*64 + lane];
      atomicAdd(&wcnt[w][v.x], 1u);
      atomicAdd(&wcnt[w][v.y], 1u);
      atomicAdd(&wcnt[w][v.z], 1u);
      atomicAdd(&wcnt[w][v.w], 1u);
      graw32[w*(SC/4) + i*64 + lane] =
        (unsigned)v.x | ((unsigned)v.y << 8) | ((unsigned)v.z << 16) | ((unsigned)v.w << 24);
    }
  }
  __syncthreads();

  // phase 2: local offsets (thread t == group id)
  {
    unsigned c0 = wcnt[0][t], c1 = wcnt[1][t], c2 = wcnt[2][t], c3 = wcnt[3][t];
    unsigned tot = c0 + c1 + c2 + c3;
    ss[t] = tot; __syncthreads();
    for (int d = 1; d < NG; d <<= 1){
      unsigned v = (t >= d) ? ss[t - d] : 0u;
      __syncthreads();
      ss[t] += v;
      __syncthreads();
    }
    unsigned lb = ss[t] - tot;              // local exclusive prefix over groups
    wcnt[0][t] = lb;
    wcnt[1][t] = lb + c0;
    wcnt[2][t] = lb + c0 + c1;
    wcnt[3][t] = lb + c0 + c1 + c2;
    bias[t] = off[(size_t)(b*NC + c)*NG + t] - lb;
  }
  __syncthreads();

  // phase 3: stable scatter into LDS (per wave, element order; g fed from LDS)
  {
    const unsigned long long below = (lane == 0) ? 0ull : ((1ull << lane) - 1ull);
    const float* psrc = pr + base + (size_t)w*SC;
    const int shft = (lane & 3) * 8;
    for (int s = 0; s < SC/64; s++){       // 16 stripes
      float p = psrc[s*64 + lane];
      // same-word broadcast read: 4 lanes share one dword, free on LDS
      unsigned packed = graw32[w*(SC/4) + s*16 + (lane >> 2)];
      int g = (int)((packed >> shft) & 255u);
      unsigned long long mask = ~0ull;
#pragma unroll
      for (int bit = 0; bit < 8; bit++){
        int bv = (g >> bit) & 1;
        unsigned long long bal = __ballot(bv);
        mask &= bv ? bal : ~bal;
      }
      int rank = __popcll(mask & below);
      unsigned old = wcnt[w][g];                 // all lanes read pre-update value
      if (rank == 0) wcnt[w][g] = old + (unsigned)__popcll(mask);
      vbuf[old + (unsigned)rank] = p;
      gbuf[old + (unsigned)rank] = (unsigned char)g;
    }
  }
  __syncthreads();

  // phase 4: coalesced flush (consecutive p -> consecutive dest within group runs)
  {
    float* dst = sorted + (size_t)b*NN;
    const unsigned* gbuf32 = (const unsigned*)gbuf;
#pragma unroll
    for (int k = 0; k < CH/256; k++){
      int p = k*256 + t;
      unsigned packed = gbuf32[p >> 2];    // broadcast within 4 threads
      unsigned g = (packed >> ((p & 3) * 8)) & 255u;
      dst[bias[g] + (unsigned)p] = vbuf[p];
    }
  }
}

// ---- Pass 4: one LANE per (batch,group); 32 lanes/block over 256 blocks so all
//      CUs participate. Double-buffered 16-element register pipeline hides load
//      latency; the fp32 add chain stays in exact element order (bit-exact). ----
__global__ __launch_bounds__(32) void k_sum(const float* __restrict__ sorted,
                                            const unsigned* __restrict__ grpbase,
                                            const unsigned* __restrict__ grplen,
                                            float* __restrict__ gsum,
                                            float* __restrict__ gmn,
                                            float* __restrict__ gmx){
  const int lane = threadIdx.x;                  // 0..31
  const int b = blockIdx.x >> 3;                 // 8 blocks per batch
  const int g = ((blockIdx.x & 7) << 5) + lane;  // one group per lane

  const unsigned base = grpbase[b*NG + g];
  const unsigned len  = grplen [b*NG + g];
  const float* sp = sorted + (size_t)b*NN + base;

  float s = 0.0f, mn = INFINITY, mx = -INFINITY;
  float A[16], C[16];
  const unsigned nfull = len >> 4;

#define LOADV(DST, K) { _Pragma("unroll") for (int j = 0; j < 16; j++) DST[j] = sp[(K)*16u + j]; }
#define CONSV(Q)      { _Pragma("unroll") for (int j = 0; j < 16; j++){ float v = Q[j]; \
                        s = __fadd_rn(s, v); mn = fminf(mn, v); mx = fmaxf(mx, v); } }

  unsigned k = 0;
  if (nfull) LOADV(A, 0)
  for (; k + 2 <= nfull; k += 2){
    LOADV(C, k + 1)              // prefetch next batch while A drains
    CONSV(A)
    if (k + 2 < nfull) LOADV(A, k + 2)
    CONSV(C)
  }
  if (k < nfull) CONSV(A)        // odd final full batch (already loaded)
  for (unsigned i = nfull << 4; i < len; i++){
    float v = sp[i];
    s = __fadd_rn(s, v);
    mn = fminf(mn, v); mx = fmaxf(mx, v);
  }
#undef LOADV
#undef CONSV

  gsum[b*NG + g] = s;
  gmn [b*NG + g] = mn;
  gmx [b*NG + g] = mx;
}

// ---- Pass 5: per-batch group pipeline (blend, stable rank, f0/f1, no_scale) ----
// params layout: SoA, params[(b*4 + comp)*NG + g]
__global__ __launch_bounds__(256) void k_pipeline(const float* __restrict__ gsum,
                                                  const float* __restrict__ gmn,
                                                  const float* __restrict__ gmx,
                                                  const float* __restrict__ inp_means,
                                                  const float* __restrict__ Wv,
                                                  float* __restrict__ params){
  const int b = blockIdx.x;
  const int g = threadIdx.x;
  __shared__ float vm[NG];
  __shared__ float vs[NG];

  const float s   = gsum[b*NG + g];   // empty group: len==0 -> s==0 (matches where(vany,...))
  const float mnf = gmn [b*NG + g];
  const float mxf = gmx [b*NG + g];
  const float W0 = Wv[0], W1 = Wv[1];
  float mean = __fdiv_rn(__fadd_rn(__fmul_rn(inp_means[b*NG + g], W0),
                                   __fmul_rn(s, W1)),
                         __fadd_rn(W0, W1));
  vm[g] = mean;
  __syncthreads();

  // stable rank == position after stable argsort
  int r = 0;
  for (int j = 0; j < NG; j++){
    float x = vm[j];
    r += (x < mean) || (x == mean && j < g);
  }
  vs[r] = mean;
  __syncthreads();

  float c0 = (r == 0)    ? vs[0]                     : vs[r-1];
  float c1 = vs[r];
  float c2 = (r == NG-1) ? __fmul_rn(vs[NG-1], 2.0f) : vs[r+1];
  float f0 = __fdiv_rn(__fadd_rn(c0, c1), 1.999f);
  float f1 = __fdiv_rn(__fadd_rn(c1, c2), 2.001f);

  bool ns = (mnf == mxf);
  params[(b*4 + 0)*NG + g] = ns ? 0.0f : mnf;                  // vmin_use
  params[(b*4 + 1)*NG + g] = ns ? 1.0f : __fsub_rn(mxf, mnf);  // range_use
  params[(b*4 + 2)*NG + g] = ns ? 1.0f : __fsub_rn(f1, f0);    // (f1-f0)_use
  params[(b*4 + 3)*NG + g] = ns ? 0.0f : f0;                   // f0_use
}

// ---- Pass 6: per-element apply, fp32 replicating reference op order ----
// params staged as 4 separate LDS arrays (b32 reads, ~2-way conflicts, vs 8-way b128)
static __device__ __forceinline__ float apply_one(float p, int g,
                                                  const float* __restrict__ sp0,
                                                  const float* __restrict__ sp1,
                                                  const float* __restrict__ sp2,
                                                  const float* __restrict__ sp3){
  float t1  = __fsub_rn(p, sp0[g]);
  float t3  = __fdiv_rn(t1, sp1[g]);
  float t5  = __fmul_rn(t3, sp2[g]);
  float tmp = __fadd_rn(t5, sp3[g]);
  bool bad = __builtin_isnan(tmp) || (tmp == 0.0f);
  float s = __fdiv_rn(p, bad ? 1.0f : tmp);
  bool bad2 = bad || __builtin_isnan(s) || __builtin_isinf(s);
  float sc = bad2 ? 0.0f : s;
  return __fmul_rn(p, sc);
}

__global__ __launch_bounds__(256) void k_apply(const float* __restrict__ pr,
                                               const int* __restrict__ vr,
                                               const float* __restrict__ params,
                                               float* __restrict__ out){
  __shared__ float sp0[NG], sp1[NG], sp2[NG], sp3[NG];
  const int t = threadIdx.x;
  const int b = blockIdx.x / CD;
  const int c = blockIdx.x % CD;

  sp0[t] = params[(b*4 + 0)*NG + t];
  sp1[t] = params[(b*4 + 1)*NG + t];
  sp2[t] = params[(b*4 + 2)*NG + t];
  sp3[t] = params[(b*4 + 3)*NG + t];
  __syncthreads();

  const size_t base = (size_t)b*NN + (size_t)c*ELD;
  const float4* p4 = (const float4*)(pr + base);
  const int4*  v4 = (const int4*)(vr + base);
  float4* o4 = (float4*)(out + base);

#pragma unroll
  for (int i = 0; i < ELD/1024; i++){
    float4 p = p4[i*256 + t];
    int4   v = v4[i*256 + t];
    float4 r;
    r.x = apply_one(p.x, v.x, sp0, sp1, sp2, sp3);
    r.y = apply_one(p.y, v.y, sp0, sp1, sp2, sp3);
    r.z = apply_one(p.z, v.z, sp0, sp1, sp2, sp3);
    r.w = apply_one(p.w, v.w, sp0, sp1, sp2, sp3);
    o4[i*256 + t] = r;
  }
}

extern "C" void kernel_launch(void* const* d_in, const int* in_sizes, int n_in,
                              void* d_out, int out_size, void* d_ws, size_t ws_size,
                              hipStream_t stream){
  const float* pr        = (const float*)d_in[0];
  const float* inp_means = (const float*)d_in[1];
  const int*   vr        = (const int*)d_in[2];
  const float* W         = (const float*)d_in[3];
  float* out = (float*)d_out;

  char* ws = (char*)d_ws;
  size_t o = 0;
  unsigned* cnt     = (unsigned*)(ws + o); o += (size_t)NB*NC*NG*4;  // 2 MB
  unsigned* grpbase = (unsigned*)(ws + o); o += (size_t)NB*NG*4;     // 32 KB
  unsigned* grplen  = (unsigned*)(ws + o); o += (size_t)NB*NG*4;
  float*    gsum    = (float*)   (ws + o); o += (size_t)NB*NG*4;
  float*    gmn     = (float*)   (ws + o); o += (size_t)NB*NG*4;
  float*    gmx     = (float*)   (ws + o); o += (size_t)NB*NG*4;
  float*    params  = (float*)   (ws + o); o += (size_t)NB*NG*16;    // 128 KB (SoA)
  // sorted values live in d_out (fully overwritten by k_apply afterwards)
  float* sorted = out;

  k_count   <<<NB*NC, 256, 0, stream>>>(vr, cnt);
  k_offsets <<<NB,     NG, 0, stream>>>(cnt, grpbase, grplen);
  k_scatter <<<NB*NC, 256, 0, stream>>>(pr, vr, cnt, sorted);
  k_sum     <<<NB*8,   32, 0, stream>>>(sorted, grpbase, grplen, gsum, gmn, gmx);
  k_pipeline<<<NB,     NG, 0, stream>>>(gsum, gmn, gmx, inp_means, W, params);
  k_apply   <<<NB*CD, 256, 0, stream>>>(pr, vr, params, out);
}